// Round 5
// baseline (5100.805 us; speedup 1.0000x reference)
//
#include <hip/hip_runtime.h>
#include <math.h>

#define Tt 16384   // B*S tokens
#define Ss 4096
#define Bb 4
#define Hh 512
#define II 1024    // INNER
#define CHUNK 32
#define NCH 128    // S / CHUNK

typedef unsigned short ushort_t;
typedef unsigned int uint_t;

__device__ __forceinline__ float sigm(float x) { return 1.0f / (1.0f + __expf(-x)); }
__device__ __forceinline__ float b2f(ushort_t h) { return __uint_as_float(((uint_t)h) << 16); }
__device__ __forceinline__ ushort_t f2b(float f) {
    uint_t u = __float_as_uint(f);
    return (ushort_t)((u + 0x7FFFu + ((u >> 16) & 1u)) >> 16);
}

struct ushort4_t { ushort_t x, y, z, w; };

__device__ __forceinline__ float4 ld4a(const float* p) {
    return *reinterpret_cast<const float4*>(p);
}
__device__ __forceinline__ float4 ld4a(const ushort_t* p) {
    ushort4_t u = *reinterpret_cast<const ushort4_t*>(p);
    float4 f;
    f.x = b2f(u.x); f.y = b2f(u.y); f.z = b2f(u.z); f.w = b2f(u.w);
    return f;
}
__device__ __forceinline__ void stc(float* p, float v)    { *p = v; }
__device__ __forceinline__ void stc(ushort_t* p, float v) { *p = f2b(v); }
__device__ __forceinline__ float ldc1(const float* p)    { return *p; }
__device__ __forceinline__ float ldc1(const ushort_t* p) { return b2f(*p); }

// ---------------------------------------------------------------------------
// Generic GEMM: C[m,n] = act( (acc? C : 0) + sum_k A[rowmap(m),k]*W[n,k] + bias[n] )
// rowmode: 0=identity, 1=partial-flip (first 2048 of each seq reversed),
//          2=shift by sh within batch (zero rows outside).
// W row-major (N x K), leading stride ldw, inner stride wstride. K % 16 == 0.
// ---------------------------------------------------------------------------
template <typename TA, typename TC>
__global__ __launch_bounds__(256) void gemm_k(
    const TA* __restrict__ A, int lda,
    const float* __restrict__ W, int ldw, int wstride,
    const float* __restrict__ bias,
    TC* __restrict__ C, int ldc,
    int N, int K, int rowmode, int sh, int accflag, int act)
{
    __shared__ float As[16][68];
    __shared__ float Ws[16][68];
    const int bm = blockIdx.y * 64;
    const int bn = blockIdx.x * 64;
    const int tid = threadIdx.x;
    const int tx = tid & 15;
    const int ty = tid >> 4;
    const int lr = tid >> 2;        // 0..63
    const int lk = (tid & 3) * 4;   // 0,4,8,12

    float acc[4][4] = {{0.f}};

    int arow = bm + lr;
    int asrc;
    {
        int b = arow >> 12;
        int s = arow & (Ss - 1);
        if (rowmode == 1) s = (s < 2048) ? (2047 - s) : s;
        else if (rowmode == 2) s += sh;
        asrc = (s < 0 || s >= Ss) ? -1 : ((b << 12) | s);
    }
    const int wn = bn + lr;

    for (int k0 = 0; k0 < K; k0 += 16) {
        float4 av = make_float4(0.f, 0.f, 0.f, 0.f);
        if (asrc >= 0)
            av = ld4a(A + (long)asrc * lda + k0 + lk);
        As[lk + 0][lr] = av.x; As[lk + 1][lr] = av.y;
        As[lk + 2][lr] = av.z; As[lk + 3][lr] = av.w;

        float4 wv = make_float4(0.f, 0.f, 0.f, 0.f);
        if (wn < N) {
            if (wstride == 1) {
                wv = *reinterpret_cast<const float4*>(W + (long)wn * ldw + k0 + lk);
            } else {
                const float* wp = W + (long)wn * ldw + (long)(k0 + lk) * wstride;
                wv.x = wp[0]; wv.y = wp[wstride]; wv.z = wp[2 * wstride]; wv.w = wp[3 * wstride];
            }
        }
        Ws[lk + 0][lr] = wv.x; Ws[lk + 1][lr] = wv.y;
        Ws[lk + 2][lr] = wv.z; Ws[lk + 3][lr] = wv.w;

        __syncthreads();
        #pragma unroll
        for (int kk = 0; kk < 16; ++kk) {
            float a[4], w[4];
            #pragma unroll
            for (int i = 0; i < 4; ++i) a[i] = As[kk][ty * 4 + i];
            #pragma unroll
            for (int j = 0; j < 4; ++j) w[j] = Ws[kk][tx * 4 + j];
            #pragma unroll
            for (int i = 0; i < 4; ++i)
                #pragma unroll
                for (int j = 0; j < 4; ++j)
                    acc[i][j] = fmaf(a[i], w[j], acc[i][j]);
        }
        __syncthreads();
    }

    #pragma unroll
    for (int i = 0; i < 4; ++i) {
        const int m = bm + ty * 4 + i;
        #pragma unroll
        for (int j = 0; j < 4; ++j) {
            const int n = bn + tx * 4 + j;
            if (n < N) {
                float v = acc[i][j];
                if (accflag) v += ldc1(C + (long)m * ldc + n);
                if (bias) v += bias[n];
                if (act == 1) v = sigm(v);
                else if (act == 2) v = v * sigm(v);
                stc(C + (long)m * ldc + n, v);
            }
        }
    }
}

// --------------------------- elementwise kernels ---------------------------

// causal depthwise conv (K=4) + silu; input = x_proj half of xz (bf16, ld 2048)
__global__ __launch_bounds__(256) void dwconv_silu_k(
    const ushort_t* __restrict__ xz, const float* __restrict__ w,
    const float* __restrict__ bias, ushort_t* __restrict__ out)
{
    const int idx = blockIdx.x * 256 + threadIdx.x;   // Tt*II
    const int c = idx & (II - 1);
    const int t = idx >> 10;
    const int s = t & (Ss - 1);
    const long rb = (long)t * 2048;
    const float w0 = w[c * 4 + 0], w1 = w[c * 4 + 1], w2 = w[c * 4 + 2], w3 = w[c * 4 + 3];
    float sum = bias[c] + b2f(xz[rb + c]) * w3;
    if (s >= 1) sum += b2f(xz[rb - 2048 + c]) * w2;
    if (s >= 2) sum += b2f(xz[rb - 2 * 2048 + c]) * w1;
    if (s >= 3) sum += b2f(xz[rb - 3 * 2048 + c]) * w0;
    out[idx] = f2b(sum * sigm(sum));
}

// per-token B/C gates from xs[:, :32] (bf16)
__global__ __launch_bounds__(256) void bgcg_k(
    const ushort_t* __restrict__ xs, float* __restrict__ bg, float* __restrict__ cg)
{
    const int t = blockIdx.x * 256 + threadIdx.x;
    if (t >= Tt) return;
    const ushort_t* p = xs + (long)t * 1056;
    float sb = 0.f, sc = 0.f;
    #pragma unroll
    for (int i = 0; i < 16; ++i) { sb += b2f(p[i]); sc += b2f(p[16 + i]); }
    bg[t] = sigm(sb * (1.f / 16.f));
    cg[t] = sigm(sc * (1.f / 16.f));
}

// dtlin(bf16) -> alpha_c (in place); gated = (1-alpha)*bgate*x_conv (bf16)
__global__ __launch_bounds__(256) void alphagate_k(
    ushort_t* __restrict__ dtlin, const ushort_t* __restrict__ xc,
    const float* __restrict__ bg, ushort_t* __restrict__ gated)
{
    const int idx = blockIdx.x * 256 + threadIdx.x;   // Tt*II
    const int t = idx >> 10;
    const float xv = b2f(dtlin[idx]);
    const float dt = (xv > 20.f) ? xv : log1pf(__expf(xv));
    const float alpha = sigm(0.1f * dt);
    const float ac = fminf(fmaxf(alpha, 0.01f), 0.99f);
    gated[idx] = f2b((1.f - alpha) * bg[t] * b2f(xc[idx]));
    dtlin[idx] = f2b(ac);
}

// scan phase 1: per (b, chunk, c) local prod + local h (bf16 in, f32 out)
__global__ __launch_bounds__(256) void scan1_k(
    const ushort_t* __restrict__ a, const ushort_t* __restrict__ g,
    float* __restrict__ ap, float* __restrict__ gs)
{
    const int idx = blockIdx.x * 256 + threadIdx.x;   // Bb*NCH*II = 524288
    const int c = idx & (II - 1);
    const int ch = (idx >> 10) & (NCH - 1);
    const int b = idx >> 17;
    const long base = ((long)(b * Ss + ch * CHUNK)) * II + c;
    float P = 1.f, h = 0.f;
    #pragma unroll 4
    for (int i = 0; i < CHUNK; ++i) {
        const float av = b2f(a[base + (long)i * II]);
        const float gv = b2f(g[base + (long)i * II]);
        P *= av;
        h = av * h + gv;
    }
    ap[idx] = P;
    gs[idx] = h;
}

// phase 2: sequential over chunks per (b,c); all f32
__global__ __launch_bounds__(256) void scan2_k(
    const float* __restrict__ ap, const float* __restrict__ gs, float* __restrict__ hin)
{
    const int idx = blockIdx.x * 256 + threadIdx.x;   // Bb*II = 4096
    if (idx >= Bb * II) return;
    const int c = idx & (II - 1);
    const int b = idx >> 10;
    float h = 0.f;
    for (int ch = 0; ch < NCH; ++ch) {
        const long j = ((long)(b * NCH + ch) << 10) + c;
        hin[j] = h;
        h = ap[j] * h + gs[j];
    }
}

// phase 3: replay chunk with true h_in; ys overwrites gated (bf16) in place
__global__ __launch_bounds__(256) void scan3_k(
    const ushort_t* __restrict__ a, ushort_t* __restrict__ g, const float* __restrict__ hin)
{
    const int idx = blockIdx.x * 256 + threadIdx.x;
    const int c = idx & (II - 1);
    const int ch = (idx >> 10) & (NCH - 1);
    const int b = idx >> 17;
    const long base = ((long)(b * Ss + ch * CHUNK)) * II + c;
    float h = hin[idx];
    #pragma unroll 4
    for (int i = 0; i < CHUNK; ++i) {
        const long o = base + (long)i * II;
        h = b2f(a[o]) * h + b2f(g[o]);
        g[o] = f2b(h);
    }
}

// y = (ys*cgate + D*x_conv) * silu(z)   (bf16 in place over ys)
__global__ __launch_bounds__(256) void yfinal_k(
    ushort_t* __restrict__ y, const float* __restrict__ cg, const float* __restrict__ D,
    const ushort_t* __restrict__ xc, const ushort_t* __restrict__ xz)
{
    const int idx = blockIdx.x * 256 + threadIdx.x;
    const int c = idx & (II - 1);
    const int t = idx >> 10;
    float v = b2f(y[idx]) * cg[t] + D[c] * b2f(xc[idx]);
    const float z = b2f(xz[(long)t * 2048 + II + c]);
    y[idx] = f2b(v * (z * sigm(z)));
}

// m_comb = gw*m_fwd + (1-gw)*m_bwd[flip(t)]  (bf16 in place over m_fwd)
__global__ __launch_bounds__(256) void mcomb_k(
    ushort_t* __restrict__ mf, const ushort_t* __restrict__ mb, const float* __restrict__ gw)
{
    const int idx = blockIdx.x * 256 + threadIdx.x;   // Tt*Hh
    const int h = idx & (Hh - 1);
    const int t = idx >> 9;
    const int s = t & (Ss - 1);
    const int b = t >> 12;
    const int sf = (s < 2048) ? (2047 - s) : s;
    const float g = gw[idx];
    const float v = g * b2f(mf[idx]) + (1.f - g) * b2f(mb[((long)((b << 12) | sf) << 9) + h]);
    mf[idx] = f2b(v);
}

// z = g*m_comb(bf16) + (1-g)*f_out(f32) -> f32
__global__ __launch_bounds__(256) void zmid_k(
    const float* __restrict__ glin, const ushort_t* __restrict__ mc,
    const float* __restrict__ fo, float* __restrict__ out)
{
    const int idx = blockIdx.x * 256 + threadIdx.x;
    const float g = glin[idx];
    out[idx] = g * b2f(mc[idx]) + (1.f - g) * fo[idx];
}

// out = LN(a + r) * gamma + beta ; one wave per token, 512 features, all f32
__global__ __launch_bounds__(256) void ln_k(
    const float* __restrict__ a, const float* __restrict__ r,
    const float* __restrict__ gam, const float* __restrict__ bet, float* __restrict__ out)
{
    const int lane = threadIdx.x & 63;
    const int wave = threadIdx.x >> 6;
    const int t = blockIdx.x * 4 + wave;
    const float* pa = a + (long)t * Hh + lane * 8;
    const float* pr = r + (long)t * Hh + lane * 8;
    float v[8];
    float s = 0.f;
    #pragma unroll
    for (int j = 0; j < 8; ++j) { v[j] = pa[j] + pr[j]; s += v[j]; }
    #pragma unroll
    for (int off = 32; off; off >>= 1) s += __shfl_xor(s, off);
    const float mean = s * (1.f / 512.f);
    float vs = 0.f;
    #pragma unroll
    for (int j = 0; j < 8; ++j) { const float d = v[j] - mean; vs += d * d; }
    #pragma unroll
    for (int off = 32; off; off >>= 1) vs += __shfl_xor(vs, off);
    const float inv = rsqrtf(vs * (1.f / 512.f) + 1e-5f);
    float* po = out + (long)t * Hh + lane * 8;
    const float* pg = gam + lane * 8;
    const float* pb = bet + lane * 8;
    #pragma unroll
    for (int j = 0; j < 8; ++j) po[j] = (v[j] - mean) * inv * pg[j] + pb[j];
}

// --------------------------- host-side helpers -----------------------------

template <typename TA, typename TC>
static inline void gemm(hipStream_t st, const TA* A, int lda, const float* W, int ldw,
                        int wstride, const float* bias, TC* C, int ldc, int N, int K,
                        int rowmode, int sh, int acc, int act)
{
    dim3 g((N + 63) / 64, Tt / 64);
    gemm_k<TA, TC><<<g, 256, 0, st>>>(A, lda, W, ldw, wstride, bias, C, ldc, N, K,
                                      rowmode, sh, acc, act);
}

static void mamba_block(hipStream_t st, const float* x, int rowmode,
                        const float* in_w, const float* conv_w, const float* conv_b,
                        const float* xproj_w, const float* dt_w, const float* dt_b,
                        const float* Dp, const float* out_w,
                        ushort_t* xz, ushort_t* xc, ushort_t* xs, ushort_t* alpha,
                        float* ap, float* gs, float* hin, float* bg, float* cg,
                        ushort_t* mout)
{
    ushort_t* gated = xs;   // overlays xs (dead after dt gemm)
    const int gEW = (Tt * II) / 256;
    // xz = x @ in_w^T (2048 out, bf16), flip folded via rowmode
    gemm(st, x, Hh, in_w, Hh, 1, (const float*)nullptr, xz, 2048, 2048, Hh, rowmode, 0, 0, 0);
    // x_conv = silu(causal dwconv(x_proj))
    dwconv_silu_k<<<gEW, 256, 0, st>>>(xz, conv_w, conv_b, xc);
    // xs = x_conv @ xproj_w^T (1056 out, bf16)
    gemm(st, xc, II, xproj_w, II, 1, (const float*)nullptr, xs, 1056, 1056, II, 0, 0, 0, 0);
    bgcg_k<<<Tt / 256, 256, 0, st>>>(xs, bg, cg);
    // dt_lin = xs[:,32:] @ dt_w^T + dt_b -> alpha buffer (bf16)
    gemm(st, xs + 32, 1056, dt_w, II, 1, dt_b, alpha, II, II, II, 0, 0, 0, 0);
    alphagate_k<<<gEW, 256, 0, st>>>(alpha, xc, bg, gated);
    // chunked scan (ys overwrites gated)
    scan1_k<<<(Bb * NCH * II) / 256, 256, 0, st>>>(alpha, gated, ap, gs);
    scan2_k<<<(Bb * II) / 256, 256, 0, st>>>(ap, gs, hin);
    scan3_k<<<(Bb * NCH * II) / 256, 256, 0, st>>>(alpha, gated, hin);
    yfinal_k<<<gEW, 256, 0, st>>>(gated, cg, Dp, xc, xz);
    // out = y @ out_w^T (bf16)
    gemm(st, gated, II, out_w, II, 1, (const float*)nullptr, mout, Hh, Hh, II, 0, 0, 0, 0);
}

extern "C" void kernel_launch(void* const* d_in, const int* in_sizes, int n_in,
                              void* d_out, int out_size, void* d_ws, size_t ws_size,
                              hipStream_t stream)
{
    const float* x       = (const float*)d_in[0];
    const float* ds_w    = (const float*)d_in[2];
    const float* ds_b    = (const float*)d_in[3];
    const float* gate_w  = (const float*)d_in[4];
    const float* gate_b  = (const float*)d_in[5];
    const float* mix_w   = (const float*)d_in[6];
    const float* mix_b   = (const float*)d_in[7];
    const float* ln_g    = (const float*)d_in[8];
    const float* ln_b    = (const float*)d_in[9];
    const float* fe_c1_w = (const float*)d_in[10];
    const float* fe_c1_b = (const float*)d_in[11];
    const float* fe_c2_w = (const float*)d_in[12];
    const float* fe_c2_b = (const float*)d_in[13];
    const float* fe_ln_g = (const float*)d_in[14];
    const float* fe_ln_b = (const float*)d_in[15];
    const float* f_in_w    = (const float*)d_in[16];
    const float* f_conv_w  = (const float*)d_in[17];
    const float* f_conv_b  = (const float*)d_in[18];
    const float* f_xproj_w = (const float*)d_in[19];
    const float* f_dt_w    = (const float*)d_in[20];
    const float* f_dt_b    = (const float*)d_in[21];
    const float* f_D       = (const float*)d_in[22];
    const float* f_out_w   = (const float*)d_in[23];
    const float* b_in_w    = (const float*)d_in[24];
    const float* b_conv_w  = (const float*)d_in[25];
    const float* b_conv_b  = (const float*)d_in[26];
    const float* b_xproj_w = (const float*)d_in[27];
    const float* b_dt_w    = (const float*)d_in[28];
    const float* b_dt_b    = (const float*)d_in[29];
    const float* b_D       = (const float*)d_in[30];
    const float* b_out_w   = (const float*)d_in[31];

    char* base = (char*)d_ws;
    // --- mamba-phase layout (total ~199 MiB) ---
    ushort_t* xz    = (ushort_t*)(base + 0L);           // Tt*2048 bf16 = 67,108,864 B
    ushort_t* xc    = (ushort_t*)(base + 67108864L);    // Tt*II bf16   = 33,554,432 B
    ushort_t* xs    = (ushort_t*)(base + 100663296L);   // Tt*1056 bf16 = 34,603,008 B
    ushort_t* alpha = (ushort_t*)(base + 135266304L);   // Tt*II bf16   = 33,554,432 B
    float*    ap    = (float*)(base + 168820736L);      // 524288 f32
    float*    gs    = (float*)(base + 170917888L);      // 524288 f32
    float*    hin   = (float*)(base + 173015040L);      // 524288 f32
    float*    bg    = (float*)(base + 175112192L);      // 16384 f32
    float*    cg    = (float*)(base + 175177728L);      // 16384 f32
    ushort_t* m_fwd = (ushort_t*)(base + 175243264L);   // Tt*Hh bf16 = 16,777,216 B
    ushort_t* m_bwd = (ushort_t*)(base + 192020480L);   // Tt*Hh bf16 = 16,777,216 B
    // --- top-path overlays (mamba scratch dead) ---
    float* gwt  = (float*)(base + 0L);                  // Tt*Hh f32
    float* c1   = (float*)(base + 33554432L);
    float* c2   = (float*)(base + 67108864L);
    float* fout = (float*)(base + 100663296L);
    float* glin = (float*)(base + 135266304L);
    float* zmid = (float*)(base + 0L);                  // after gwt dead
    float* zmix = (float*)(base + 33554432L);           // after c1 dead

    const int gH = (Tt * Hh) / 256;

    // 1-2. mamba fwd / bwd (bwd: flip folded into first GEMM + output read)
    mamba_block(stream, x, 0, f_in_w, f_conv_w, f_conv_b, f_xproj_w, f_dt_w, f_dt_b,
                f_D, f_out_w, xz, xc, xs, alpha, ap, gs, hin, bg, cg, m_fwd);
    mamba_block(stream, x, 1, b_in_w, b_conv_w, b_conv_b, b_xproj_w, b_dt_w, b_dt_b,
                b_D, b_out_w, xz, xc, xs, alpha, ap, gs, hin, bg, cg, m_bwd);

    // 3. gate_weights = sigmoid(x @ ds_w^T + ds_b)  (into now-dead scratch)
    gemm(stream, x, Hh, ds_w, Hh, 1, ds_b, gwt, Hh, Hh, Hh, 0, 0, 0, 1);

    // 4. feature path: c1 = silu(conv3(x)), c2 = conv3(c1), f_out = LN(c2 + x)
    for (int k = 0; k < 3; ++k)
        gemm(stream, x, Hh, fe_c1_w + k, 1536, 3, (k == 2) ? fe_c1_b : (const float*)nullptr,
             c1, Hh, Hh, Hh, 2, k - 1, (k > 0) ? 1 : 0, (k == 2) ? 2 : 0);
    for (int k = 0; k < 3; ++k)
        gemm(stream, c1, Hh, fe_c2_w + k, 1536, 3, (k == 2) ? fe_c2_b : (const float*)nullptr,
             c2, Hh, Hh, Hh, 2, k - 1, (k > 0) ? 1 : 0, 0);
    ln_k<<<Tt / 4, 256, 0, stream>>>(c2, x, fe_ln_g, fe_ln_b, fout);

    // 5. m_comb (in place over m_fwd, bf16; reads m_bwd at flipped rows)
    mcomb_k<<<gH, 256, 0, stream>>>(m_fwd, m_bwd, gwt);

    // 6. g = sigmoid([m_comb, f_out] @ gate_w^T + gate_b)  (two-pass accumulate)
    gemm(stream, m_fwd, Hh, gate_w, 1024, 1, (const float*)nullptr, glin, Hh, Hh, Hh, 0, 0, 0, 0);
    gemm(stream, fout, Hh, gate_w + 512, 1024, 1, gate_b, glin, Hh, Hh, Hh, 0, 0, 1, 1);

    // 7. z = g*m_comb + (1-g)*f_out  (zmid overlays dead gwt)
    zmid_k<<<gH, 256, 0, stream>>>(glin, m_fwd, fout, zmid);

    // 8. z = z @ mix_w^T + mix_b  (zmix overlays dead c1)
    gemm(stream, zmid, Hh, mix_w, Hh, 1, mix_b, zmix, Hh, Hh, Hh, 0, 0, 0, 0);

    // 9. out = LN(z + x)
    ln_k<<<Tt / 4, 256, 0, stream>>>(zmix, x, ln_g, ln_b, (float*)d_out);
}

// Round 6
// 1372.580 us; speedup vs baseline: 3.7162x; 3.7162x over previous
//
#include <hip/hip_runtime.h>
#include <math.h>

#define Tt 16384   // B*S tokens
#define Ss 4096
#define Bb 4
#define Hh 512
#define II 1024    // INNER
#define CHUNK 32
#define NCH 128    // S / CHUNK
#define SP 4098    // Ss + 2 halo rows per batch

typedef unsigned short ushort_t;
typedef unsigned int uint_t;
typedef __attribute__((ext_vector_type(8))) short bf16x8;
typedef __attribute__((ext_vector_type(4))) short bf16x4;
typedef __attribute__((ext_vector_type(4))) float f32x4;

__device__ __forceinline__ float sigm(float x) { return 1.0f / (1.0f + __expf(-x)); }
__device__ __forceinline__ float b2f(ushort_t h) { return __uint_as_float(((uint_t)h) << 16); }
__device__ __forceinline__ ushort_t f2b(float f) {
    uint_t u = __float_as_uint(f);
    return (ushort_t)((u + 0x7FFFu + ((u >> 16) & 1u)) >> 16);
}
__device__ __forceinline__ void stc(float* p, float v)    { *p = v; }
__device__ __forceinline__ void stc(ushort_t* p, float v) { *p = f2b(v); }
__device__ __forceinline__ float ldc1(const float* p)    { return *p; }
__device__ __forceinline__ float ldc1(const ushort_t* p) { return b2f(*p); }

// async global->LDS, 16B per lane; LDS dest = wave-uniform base + lane*16
__device__ __forceinline__ void gload16(const void* g, void* l) {
    __builtin_amdgcn_global_load_lds(
        (const __attribute__((address_space(1))) unsigned int*)g,
        (__attribute__((address_space(3))) unsigned int*)l,
        16, 0, 0);
}

// ---------------------------------------------------------------------------
// MFMA bf16 GEMM, 128x128 tile, BK=32, 4 waves (each 64x64), m97 structure.
// C[m,n] = act( sum_k A[rowmap(m),k] * W[n,k] + bias[n] )
// amode: 0 linear (lda given)
//        1 flip-halo : A=xpad, row=(b*SP + flip(s) + 1)*512
//        2 lin-halo  : A=xpad, row=(b*SP + s + 1)*512
//        3 conv-halo : A=pad buffer, row=(b*SP + s)*512, K spans 3 taps linearly
//        4 concat    : A0 for k<512, A1 for k>=512, lda=512
// smode: 0 linear store, 1 halo store (row = b*SP + s + 1, for c1pad)
// act: 0 none, 1 sigmoid, 2 silu.  cbf16: C is bf16 else f32.
// Grid: (PN/128, Tt/128). W must have PN valid (zero-padded) rows.
// ---------------------------------------------------------------------------
__global__ __launch_bounds__(256) void mfma_gemm(
    const ushort_t* __restrict__ A, const ushort_t* __restrict__ A1, int lda,
    const ushort_t* __restrict__ W, int ldw,
    const float* __restrict__ bias,
    void* __restrict__ Cv, int ldc, int Nreal, int K,
    int amode, int act, int smode, int cbf16)
{
    __shared__ __align__(16) ushort_t As[128 * 32];
    __shared__ __align__(16) ushort_t Bs[128 * 32];
    const int tid  = threadIdx.x;
    const int lane = tid & 63;
    const int wid  = tid >> 6;
    const int bm   = blockIdx.y * 128;
    const int bn   = blockIdx.x * 128;
    const int wr   = wid >> 1;
    const int wc   = wid & 1;

    // ---- staging address precompute (per lane, 2 rounds of 16 rows/wave) ----
    const int colA = (lane & 3) * 8;   // element offset within 32-wide k tile
    long gA[2], gW[2];
    #pragma unroll
    for (int r = 0; r < 2; ++r) {
        const int rt = (r * 4 + wid) * 16 + (lane >> 2);   // tile row 0..127
        const int t  = bm + rt;
        const int b  = t >> 12;
        const int s  = t & (Ss - 1);
        long rowoff;
        if (amode == 0)      rowoff = (long)t * lda;
        else if (amode == 1) { const int sf = (s < 2048) ? (2047 - s) : s;
                               rowoff = (long)(b * SP + sf + 1) * 512; }
        else if (amode == 2) rowoff = (long)(b * SP + s + 1) * 512;
        else if (amode == 3) rowoff = (long)(b * SP + s) * 512;
        else                 rowoff = (long)t * 512;
        gA[r] = rowoff + colA;
        gW[r] = (long)(bn + rt) * ldw + colA;
    }

    // ---- fragment read offsets (A: row=lane&15, k=(lane>>4)*8; B symmetric) ----
    const int aoff = (wr * 64 + (lane & 15)) * 32 + (lane >> 4) * 8;
    const int boff = (wc * 64 + (lane & 15)) * 32 + (lane >> 4) * 8;

    f32x4 acc[4][4] = {};

    for (int k0 = 0; k0 < K; k0 += 32) {
        const ushort_t* pA = A;
        long kadd = k0;
        if (amode == 4) { pA = (k0 < 512) ? A : A1; kadd = k0 & 511; }
        #pragma unroll
        for (int r = 0; r < 2; ++r) {
            gload16(pA + gA[r] + kadd, &As[(r * 4 + wid) * 512]);
            gload16(W + gW[r] + k0,    &Bs[(r * 4 + wid) * 512]);
        }
        __syncthreads();   // drains vmcnt before use

        bf16x8 af[4], bfr[4];
        #pragma unroll
        for (int mi = 0; mi < 4; ++mi) af[mi]  = *(const bf16x8*)&As[aoff + mi * 512];
        #pragma unroll
        for (int ni = 0; ni < 4; ++ni) bfr[ni] = *(const bf16x8*)&Bs[boff + ni * 512];
        #pragma unroll
        for (int mi = 0; mi < 4; ++mi)
            #pragma unroll
            for (int ni = 0; ni < 4; ++ni)
                acc[mi][ni] = __builtin_amdgcn_mfma_f32_16x16x32_bf16(
                    af[mi], bfr[ni], acc[mi][ni], 0, 0, 0);
        __syncthreads();   // before next-tile overwrite
    }

    // ---- epilogue: C/D layout col=lane&15, row=(lane>>4)*4+r ----
    float* Cf = (float*)Cv;
    ushort_t* Cb = (ushort_t*)Cv;
    #pragma unroll
    for (int mi = 0; mi < 4; ++mi) {
        const int row0 = bm + wr * 64 + mi * 16 + (lane >> 4) * 4;
        #pragma unroll
        for (int ni = 0; ni < 4; ++ni) {
            const int col = bn + wc * 64 + ni * 16 + (lane & 15);
            if (col < Nreal) {
                const float bv = bias ? bias[col] : 0.f;
                #pragma unroll
                for (int r = 0; r < 4; ++r) {
                    float v = acc[mi][ni][r] + bv;
                    if (act == 1) v = sigm(v);
                    else if (act == 2) v = v * sigm(v);
                    const int t = row0 + r;
                    long crow;
                    if (smode == 1) { const int b = t >> 12, s = t & (Ss - 1);
                                      crow = (long)(b * SP + s + 1); }
                    else crow = t;
                    if (cbf16) Cb[crow * ldc + col] = f2b(v);
                    else       Cf[crow * ldc + col] = v;
                }
            }
        }
    }
}

// --------------------------- convert kernels -------------------------------

// x f32 -> xpad bf16 with zero halo rows (sp=0 and sp=SP-1 per batch)
__global__ __launch_bounds__(256) void cvt_x_pad(
    const float* __restrict__ x, ushort_t* __restrict__ xpad)
{
    const int idx = blockIdx.x * 256 + threadIdx.x;   // Bb*SP*64
    const int c8 = (idx & 63) * 8;
    const int sp = (idx >> 6) % SP;
    const int b  = idx / (64 * SP);
    bf16x8 v;
    if (sp == 0 || sp == SP - 1) {
        v = (bf16x8)0;
    } else {
        const float* p = x + ((long)(b * Ss + sp - 1)) * 512 + c8;
        #pragma unroll
        for (int j = 0; j < 8; ++j) v[j] = (short)f2b(p[j]);
    }
    *(bf16x8*)&xpad[((long)(b * SP + sp)) * 512 + c8] = v;
}

// plain f32 -> bf16 (n4 = count/4)
__global__ __launch_bounds__(256) void cvt_plain(
    const float* __restrict__ s, ushort_t* __restrict__ d, int n4)
{
    const int i = blockIdx.x * 256 + threadIdx.x;
    if (i >= n4) return;
    const float4 f = *(const float4*)&s[(long)i * 4];
    bf16x4 v;
    v[0] = (short)f2b(f.x); v[1] = (short)f2b(f.y);
    v[2] = (short)f2b(f.z); v[3] = (short)f2b(f.w);
    *(bf16x4*)&d[(long)i * 4] = v;
}

// xproj W [1056][1024] f32 -> [1152][1024] bf16 (rows >=1056 zero)
__global__ __launch_bounds__(256) void cvt_xproj(
    const float* __restrict__ s, ushort_t* __restrict__ d)
{
    const int i = blockIdx.x * 256 + threadIdx.x;   // 1152*1024/4
    const long e = (long)i * 4;
    const int n = (int)(e >> 10);
    bf16x4 v = (bf16x4)0;
    if (n < 1056) {
        const float4 f = *(const float4*)&s[e];
        v[0] = (short)f2b(f.x); v[1] = (short)f2b(f.y);
        v[2] = (short)f2b(f.z); v[3] = (short)f2b(f.w);
    }
    *(bf16x4*)&d[e] = v;
}

// fe conv W (512,512,3) f32 -> [512][tap*512+c] bf16
__global__ __launch_bounds__(256) void cvt_fe(
    const float* __restrict__ s, ushort_t* __restrict__ d)
{
    const int idx = blockIdx.x * 256 + threadIdx.x;   // 512*1536
    const int n = idx / 1536;
    const int rem = idx - n * 1536;
    const int j = rem >> 9;
    const int c = rem & 511;
    d[idx] = f2b(s[((long)n * 512 + c) * 3 + j]);
}

// zero the halo rows of c1pad
__global__ __launch_bounds__(256) void zero_halo(ushort_t* __restrict__ p)
{
    const int i = blockIdx.x * 256 + threadIdx.x;   // Bb*2*64 = 512
    const int c8 = (i & 63) * 8;
    const int h = (i >> 6) & 1;
    const int b = i >> 7;
    const long row = (long)b * SP + (h ? SP - 1 : 0);
    *(bf16x8*)&p[row * 512 + c8] = (bf16x8)0;
}

// --------------------------- elementwise kernels ---------------------------

__global__ __launch_bounds__(256) void dwconv_silu_k(
    const ushort_t* __restrict__ xz, const float* __restrict__ w,
    const float* __restrict__ bias, ushort_t* __restrict__ out)
{
    const int idx = blockIdx.x * 256 + threadIdx.x;   // Tt*II
    const int c = idx & (II - 1);
    const int t = idx >> 10;
    const int s = t & (Ss - 1);
    const long rb = (long)t * 2048;
    const float w0 = w[c * 4 + 0], w1 = w[c * 4 + 1], w2 = w[c * 4 + 2], w3 = w[c * 4 + 3];
    float sum = bias[c] + b2f(xz[rb + c]) * w3;
    if (s >= 1) sum += b2f(xz[rb - 2048 + c]) * w2;
    if (s >= 2) sum += b2f(xz[rb - 2 * 2048 + c]) * w1;
    if (s >= 3) sum += b2f(xz[rb - 3 * 2048 + c]) * w0;
    out[idx] = f2b(sum * sigm(sum));
}

__global__ __launch_bounds__(256) void bgcg_k(
    const ushort_t* __restrict__ xs, float* __restrict__ bg, float* __restrict__ cg)
{
    const int t = blockIdx.x * 256 + threadIdx.x;
    if (t >= Tt) return;
    const ushort_t* p = xs + (long)t * 1056;
    float sb = 0.f, sc = 0.f;
    #pragma unroll
    for (int i = 0; i < 16; ++i) { sb += b2f(p[i]); sc += b2f(p[16 + i]); }
    bg[t] = sigm(sb * (1.f / 16.f));
    cg[t] = sigm(sc * (1.f / 16.f));
}

__global__ __launch_bounds__(256) void alphagate_k(
    ushort_t* __restrict__ dtlin, const ushort_t* __restrict__ xc,
    const float* __restrict__ bg, ushort_t* __restrict__ gated)
{
    const int idx = blockIdx.x * 256 + threadIdx.x;   // Tt*II
    const int t = idx >> 10;
    const float xv = b2f(dtlin[idx]);
    const float dt = (xv > 20.f) ? xv : log1pf(__expf(xv));
    const float alpha = sigm(0.1f * dt);
    const float ac = fminf(fmaxf(alpha, 0.01f), 0.99f);
    gated[idx] = f2b((1.f - alpha) * bg[t] * b2f(xc[idx]));
    dtlin[idx] = f2b(ac);
}

__global__ __launch_bounds__(256) void scan1_k(
    const ushort_t* __restrict__ a, const ushort_t* __restrict__ g,
    float* __restrict__ ap, float* __restrict__ gs)
{
    const int idx = blockIdx.x * 256 + threadIdx.x;   // Bb*NCH*II
    const int c = idx & (II - 1);
    const int ch = (idx >> 10) & (NCH - 1);
    const int b = idx >> 17;
    const long base = ((long)(b * Ss + ch * CHUNK)) * II + c;
    float P = 1.f, h = 0.f;
    #pragma unroll 4
    for (int i = 0; i < CHUNK; ++i) {
        const float av = b2f(a[base + (long)i * II]);
        const float gv = b2f(g[base + (long)i * II]);
        P *= av;
        h = av * h + gv;
    }
    ap[idx] = P;
    gs[idx] = h;
}

__global__ __launch_bounds__(256) void scan2_k(
    const float* __restrict__ ap, const float* __restrict__ gs, float* __restrict__ hin)
{
    const int idx = blockIdx.x * 256 + threadIdx.x;   // Bb*II
    if (idx >= Bb * II) return;
    const int c = idx & (II - 1);
    const int b = idx >> 10;
    float h = 0.f;
    for (int ch = 0; ch < NCH; ++ch) {
        const long j = ((long)(b * NCH + ch) << 10) + c;
        hin[j] = h;
        h = ap[j] * h + gs[j];
    }
}

__global__ __launch_bounds__(256) void scan3_k(
    const ushort_t* __restrict__ a, ushort_t* __restrict__ g, const float* __restrict__ hin)
{
    const int idx = blockIdx.x * 256 + threadIdx.x;
    const int c = idx & (II - 1);
    const int ch = (idx >> 10) & (NCH - 1);
    const int b = idx >> 17;
    const long base = ((long)(b * Ss + ch * CHUNK)) * II + c;
    float h = hin[idx];
    #pragma unroll 4
    for (int i = 0; i < CHUNK; ++i) {
        const long o = base + (long)i * II;
        h = b2f(a[o]) * h + b2f(g[o]);
        g[o] = f2b(h);
    }
}

__global__ __launch_bounds__(256) void yfinal_k(
    ushort_t* __restrict__ y, const float* __restrict__ cg, const float* __restrict__ D,
    const ushort_t* __restrict__ xc, const ushort_t* __restrict__ xz)
{
    const int idx = blockIdx.x * 256 + threadIdx.x;
    const int c = idx & (II - 1);
    const int t = idx >> 10;
    float v = b2f(y[idx]) * cg[t] + D[c] * b2f(xc[idx]);
    const float z = b2f(xz[(long)t * 2048 + II + c]);
    y[idx] = f2b(v * (z * sigm(z)));
}

// m_comb = gw*m_fwd + (1-gw)*m_bwd[flip]  (bf16 in place; gw bf16)
__global__ __launch_bounds__(256) void mcomb_k(
    ushort_t* __restrict__ mf, const ushort_t* __restrict__ mb,
    const ushort_t* __restrict__ gw)
{
    const int idx = blockIdx.x * 256 + threadIdx.x;   // Tt*Hh
    const int h = idx & (Hh - 1);
    const int t = idx >> 9;
    const int s = t & (Ss - 1);
    const int b = t >> 12;
    const int sf = (s < 2048) ? (2047 - s) : s;
    const float g = b2f(gw[idx]);
    const float v = g * b2f(mf[idx]) + (1.f - g) * b2f(mb[((long)((b << 12) | sf) << 9) + h]);
    mf[idx] = f2b(v);
}

// z = g*m_comb + (1-g)*f_out   (all bf16)
__global__ __launch_bounds__(256) void zmid_k(
    const ushort_t* __restrict__ glin, const ushort_t* __restrict__ mc,
    const ushort_t* __restrict__ fo, ushort_t* __restrict__ out)
{
    const int idx = blockIdx.x * 256 + threadIdx.x;
    const float g = b2f(glin[idx]);
    out[idx] = f2b(g * b2f(mc[idx]) + (1.f - g) * b2f(fo[idx]));
}

// out = LN(a + r) * gamma + beta ; one wave per token, 512 features
template <typename TA, typename TO>
__global__ __launch_bounds__(256) void ln_k(
    const TA* __restrict__ a, const float* __restrict__ r,
    const float* __restrict__ gam, const float* __restrict__ bet, TO* __restrict__ out)
{
    const int lane = threadIdx.x & 63;
    const int wave = threadIdx.x >> 6;
    const int t = blockIdx.x * 4 + wave;
    const TA* pa = a + (long)t * Hh + lane * 8;
    const float* pr = r + (long)t * Hh + lane * 8;
    float v[8];
    float s = 0.f;
    #pragma unroll
    for (int j = 0; j < 8; ++j) { v[j] = ldc1(&pa[j]) + pr[j]; s += v[j]; }
    #pragma unroll
    for (int off = 32; off; off >>= 1) s += __shfl_xor(s, off);
    const float mean = s * (1.f / 512.f);
    float vs = 0.f;
    #pragma unroll
    for (int j = 0; j < 8; ++j) { const float d = v[j] - mean; vs += d * d; }
    #pragma unroll
    for (int off = 32; off; off >>= 1) vs += __shfl_xor(vs, off);
    const float inv = rsqrtf(vs * (1.f / 512.f) + 1e-5f);
    TO* po = out + (long)t * Hh + lane * 8;
    const float* pg = gam + lane * 8;
    const float* pb = bet + lane * 8;
    #pragma unroll
    for (int j = 0; j < 8; ++j) stc(&po[j], (v[j] - mean) * inv * pg[j] + pb[j]);
}

// --------------------------- host-side helpers -----------------------------

static inline void gemm(hipStream_t st, const ushort_t* A, const ushort_t* A1, int lda,
                        const ushort_t* W, int ldw, const float* bias,
                        void* C, int ldc, int Nreal, int PN, int K,
                        int amode, int act, int smode, int cbf16)
{
    dim3 g(PN / 128, Tt / 128);
    mfma_gemm<<<g, 256, 0, st>>>(A, A1, lda, W, ldw, bias, C, ldc, Nreal, K,
                                 amode, act, smode, cbf16);
}

static void mamba_block(hipStream_t st, const ushort_t* xpad, int amode_in,
                        const ushort_t* w_in, const float* conv_w, const float* conv_b,
                        const ushort_t* w_xp, const ushort_t* w_dt, const float* dt_b,
                        const float* Dp, const ushort_t* w_out,
                        ushort_t* xz, ushort_t* xc, ushort_t* xs, ushort_t* alpha,
                        float* ap, float* gs, float* hin, float* bg, float* cg,
                        ushort_t* mout)
{
    ushort_t* gated = xs;   // overlays xs (dead after dt gemm + bgcg)
    const int gEW = (Tt * II) / 256;
    gemm(st, xpad, nullptr, 512, w_in, 512, nullptr, xz, 2048, 2048, 2048, 512,
         amode_in, 0, 0, 1);
    dwconv_silu_k<<<gEW, 256, 0, st>>>(xz, conv_w, conv_b, xc);
    gemm(st, xc, nullptr, 1024, w_xp, 1024, nullptr, xs, 1056, 1056, 1152, 1024,
         0, 0, 0, 1);
    bgcg_k<<<Tt / 256, 256, 0, st>>>(xs, bg, cg);
    gemm(st, xs + 32, nullptr, 1056, w_dt, 1024, dt_b, alpha, 1024, 1024, 1024, 1024,
         0, 0, 0, 1);
    alphagate_k<<<gEW, 256, 0, st>>>(alpha, xc, bg, gated);
    scan1_k<<<(Bb * NCH * II) / 256, 256, 0, st>>>(alpha, gated, ap, gs);
    scan2_k<<<(Bb * II) / 256, 256, 0, st>>>(ap, gs, hin);
    scan3_k<<<(Bb * NCH * II) / 256, 256, 0, st>>>(alpha, gated, hin);
    yfinal_k<<<gEW, 256, 0, st>>>(gated, cg, Dp, xc, xz);
    gemm(st, gated, nullptr, 1024, w_out, 1024, nullptr, mout, 512, 512, 512, 1024,
         0, 0, 0, 1);
}

extern "C" void kernel_launch(void* const* d_in, const int* in_sizes, int n_in,
                              void* d_out, int out_size, void* d_ws, size_t ws_size,
                              hipStream_t stream)
{
    const float* x       = (const float*)d_in[0];
    const float* ds_w    = (const float*)d_in[2];
    const float* ds_b    = (const float*)d_in[3];
    const float* gate_w  = (const float*)d_in[4];
    const float* gate_b  = (const float*)d_in[5];
    const float* mix_w   = (const float*)d_in[6];
    const float* mix_b   = (const float*)d_in[7];
    const float* ln_g    = (const float*)d_in[8];
    const float* ln_b    = (const float*)d_in[9];
    const float* fe_c1_w = (const float*)d_in[10];
    const float* fe_c1_b = (const float*)d_in[11];
    const float* fe_c2_w = (const float*)d_in[12];
    const float* fe_c2_b = (const float*)d_in[13];
    const float* fe_ln_g = (const float*)d_in[14];
    const float* fe_ln_b = (const float*)d_in[15];
    const float* f_in_w    = (const float*)d_in[16];
    const float* f_conv_w  = (const float*)d_in[17];
    const float* f_conv_b  = (const float*)d_in[18];
    const float* f_xproj_w = (const float*)d_in[19];
    const float* f_dt_w    = (const float*)d_in[20];
    const float* f_dt_b    = (const float*)d_in[21];
    const float* f_D       = (const float*)d_in[22];
    const float* f_out_w   = (const float*)d_in[23];
    const float* b_in_w    = (const float*)d_in[24];
    const float* b_conv_w  = (const float*)d_in[25];
    const float* b_conv_b  = (const float*)d_in[26];
    const float* b_xproj_w = (const float*)d_in[27];
    const float* b_dt_w    = (const float*)d_in[28];
    const float* b_dt_b    = (const float*)d_in[29];
    const float* b_D       = (const float*)d_in[30];
    const float* b_out_w   = (const float*)d_in[31];

    char* base = (char*)d_ws;
    // --- mamba-phase layout ---
    ushort_t* xz    = (ushort_t*)(base + 0L);           // Tt*2048 bf16 = 67,108,864
    ushort_t* xc    = (ushort_t*)(base + 67108864L);    // Tt*II bf16   = 33,554,432
    ushort_t* xs    = (ushort_t*)(base + 100663296L);   // Tt*1056 bf16 = 34,603,008
    ushort_t* alpha = (ushort_t*)(base + 135266304L);   // Tt*II bf16   = 33,554,432
    float*    ap    = (float*)(base + 168820736L);
    float*    gs    = (float*)(base + 170917888L);
    float*    hin   = (float*)(base + 173015040L);
    float*    bg    = (float*)(base + 175112192L);
    float*    cg    = (float*)(base + 175177728L);
    ushort_t* m_fwd = (ushort_t*)(base + 175243264L);   // Tt*Hh bf16
    ushort_t* m_bwd = (ushort_t*)(base + 192020480L);   // Tt*Hh bf16
    ushort_t* xpad  = (ushort_t*)(base + 208797696L);   // Bb*SP*512 bf16 = 16,785,408
    // --- bf16 weights (persist) ---
    ushort_t* w_fin  = (ushort_t*)(base + 225583104L);  // 2048x512
    ushort_t* w_bin  = (ushort_t*)(base + 227680256L);  // 2048x512
    ushort_t* w_fxp  = (ushort_t*)(base + 229777408L);  // 1152x1024 (padded)
    ushort_t* w_bxp  = (ushort_t*)(base + 232136704L);
    ushort_t* w_fdt  = (ushort_t*)(base + 234496000L);  // 1024x1024
    ushort_t* w_bdt  = (ushort_t*)(base + 236593152L);
    ushort_t* w_fout = (ushort_t*)(base + 238690304L);  // 512x1024
    ushort_t* w_bout = (ushort_t*)(base + 239738880L);
    ushort_t* w_ds   = (ushort_t*)(base + 240787456L);  // 512x512
    ushort_t* w_gate = (ushort_t*)(base + 241311744L);  // 512x1024
    ushort_t* w_mix  = (ushort_t*)(base + 242360320L);  // 512x512
    ushort_t* w_fc1  = (ushort_t*)(base + 242884608L);  // 512x1536 (reshaped)
    ushort_t* w_fc2  = (ushort_t*)(base + 244457472L);  // end 246,030,336
    // --- top-path overlays (mamba scratch dead) ---
    ushort_t* gwt   = (ushort_t*)(base + 0L);           // Tt*Hh bf16
    ushort_t* c1pad = (ushort_t*)(base + 16777216L);    // Bb*SP*512 bf16
    ushort_t* c2    = (ushort_t*)(base + 33562624L);    // Tt*Hh bf16
    ushort_t* fout  = (ushort_t*)(base + 50339840L);    // Tt*Hh bf16
    ushort_t* glin  = (ushort_t*)(base + 67117056L);    // Tt*Hh bf16
    ushort_t* zmidb = (ushort_t*)(base + 83894272L);    // Tt*Hh bf16
    float*    zmix  = (float*)(base + 100671488L);      // Tt*Hh f32

    const int gH = (Tt * Hh) / 256;

    // 0. converts: x -> halo-padded bf16; all weights -> bf16
    cvt_x_pad<<<(Bb * SP * 64) / 256, 256, 0, stream>>>(x, xpad);
    cvt_plain<<<1024, 256, 0, stream>>>(f_in_w, w_fin, 262144);
    cvt_plain<<<1024, 256, 0, stream>>>(b_in_w, w_bin, 262144);
    cvt_xproj<<<1152, 256, 0, stream>>>(f_xproj_w, w_fxp);
    cvt_xproj<<<1152, 256, 0, stream>>>(b_xproj_w, w_bxp);
    cvt_plain<<<1024, 256, 0, stream>>>(f_dt_w, w_fdt, 262144);
    cvt_plain<<<1024, 256, 0, stream>>>(b_dt_w, w_bdt, 262144);
    cvt_plain<<<512, 256, 0, stream>>>(f_out_w, w_fout, 131072);
    cvt_plain<<<512, 256, 0, stream>>>(b_out_w, w_bout, 131072);
    cvt_plain<<<256, 256, 0, stream>>>(ds_w, w_ds, 65536);
    cvt_plain<<<512, 256, 0, stream>>>(gate_w, w_gate, 131072);
    cvt_plain<<<256, 256, 0, stream>>>(mix_w, w_mix, 65536);
    cvt_fe<<<3072, 256, 0, stream>>>(fe_c1_w, w_fc1);
    cvt_fe<<<3072, 256, 0, stream>>>(fe_c2_w, w_fc2);

    // 1-2. mamba fwd (amode 2: linear halo) / bwd (amode 1: flip halo)
    mamba_block(stream, xpad, 2, w_fin, f_conv_w, f_conv_b, w_fxp, w_fdt, f_dt_b,
                f_D, w_fout, xz, xc, xs, alpha, ap, gs, hin, bg, cg, m_fwd);
    mamba_block(stream, xpad, 1, w_bin, b_conv_w, b_conv_b, w_bxp, w_bdt, b_dt_b,
                b_D, w_bout, xz, xc, xs, alpha, ap, gs, hin, bg, cg, m_bwd);

    // 3. gate_weights = sigmoid(x @ ds_w^T + ds_b)   (bf16, overlays dead xz)
    gemm(stream, xpad, nullptr, 512, w_ds, 512, ds_b, gwt, 512, 512, 512, 512,
         2, 1, 0, 1);

    // 4. feature path: c1 = silu(conv3(x)) into halo layout; c2 = conv3(c1); LN
    zero_halo<<<2, 256, 0, stream>>>(c1pad);
    gemm(stream, xpad, nullptr, 512, w_fc1, 1536, fe_c1_b, c1pad, 512, 512, 512, 1536,
         3, 2, 1, 1);
    gemm(stream, c1pad, nullptr, 512, w_fc2, 1536, fe_c2_b, c2, 512, 512, 512, 1536,
         3, 0, 0, 1);
    ln_k<ushort_t, ushort_t><<<Tt / 4, 256, 0, stream>>>(c2, x, fe_ln_g, fe_ln_b, fout);

    // 5. m_comb (in place over m_fwd)
    mcomb_k<<<gH, 256, 0, stream>>>(m_fwd, m_bwd, gwt);

    // 6. g = sigmoid([m_comb, f_out] @ gate_w^T + gate_b)  (concat-A, one pass)
    gemm(stream, m_fwd, fout, 512, w_gate, 1024, gate_b, glin, 512, 512, 512, 1024,
         4, 1, 0, 1);

    // 7. z = g*m_comb + (1-g)*f_out
    zmid_k<<<gH, 256, 0, stream>>>(glin, m_fwd, fout, zmidb);

    // 8. z = z @ mix_w^T + mix_b  (f32 out)
    gemm(stream, zmidb, nullptr, 512, w_mix, 512, mix_b, zmix, 512, 512, 512, 512,
         0, 0, 0, 0);

    // 9. out = LN(z + x)
    ln_k<float, float><<<Tt / 4, 256, 0, stream>>>(zmix, x, ln_g, ln_b, (float*)d_out);
}